// Round 5
// baseline (354.767 us; speedup 1.0000x reference)
//
#include <hip/hip_runtime.h>
#include <stdint.h>

// LFreqEmbed — ROUND 10: odd-levels direct-from-X + 256x128 8-wave GEMM.
// Round-9 post-mortem: counted vmcnt worked (gemm <92us, est ~85); top-5 now
// all harness poison fills (~92us, fixed floor ~165us with launch/memsets).
// Levers:
//  1. Odd-level G rows are CONTIGUOUS runs of X (row-crossing term cancels:
//     addr = b*150528 + c*50176 + (111+l)*224 + kk). bf16 mode: gemm stages
//     odd rows straight from X (addr(t) = base + t*64 + c*49728); pack only
//     does the transpose half + bias; W used in place. F32 mode: full pack.
//  2. GEMM 256x128 tile, 8 waves, same counted-vmcnt protocol (vmcnt(6));
//     FLOP/staged-byte 64->85; LDS 96KB, grid 672.

#define IMG   224
#define NLEV  112
#define CIN   3
#define DIN   1344
#define EMB   768
#define BATCH 256
#define MTOT  28672
#define NT    21          // DIN/64 K-steps
#define GBM   256
#define GBN   128

// fallback (round-5 fused kernel) tile params
#define BM    128
#define BN    128
#define BK    64
#define LDP   72

#define AS1 __attribute__((address_space(1)))
#define AS3 __attribute__((address_space(3)))

typedef __attribute__((ext_vector_type(8))) short   short8;
typedef __attribute__((ext_vector_type(4))) float   floatx4;

__device__ __forceinline__ unsigned short f2bf(float f) {
    unsigned u = __float_as_uint(f);
    unsigned r = (u + 0x7fffu + ((u >> 16) & 1u)) >> 16;
    return (unsigned short)r;
}
__device__ __forceinline__ float bf2f(unsigned short s) {
    return __uint_as_float(((unsigned)s) << 16);
}
__device__ __forceinline__ unsigned pack2(float a, float b) {
    return (unsigned)f2bf(a) | ((unsigned)f2bf(b) << 16);
}

// dtype probe (fallback path): bf16 inputs -> W[2k] real weights (<0x4000);
// f32 inputs -> mantissa halves (uniform bits).
__global__ void detect_dtype(const unsigned short* __restrict__ W, int* flag) {
    __shared__ int s;
    if (threadIdx.x == 0) s = 0;
    __syncthreads();
    int bad = 0;
    for (int k = threadIdx.x; k < 4096; k += 256) {
        unsigned v = (unsigned)W[2 * k] & 0x7FFFu;
        if (v >= 0x4000u) bad = 1;
    }
    if (bad) atomicOr(&s, 1);
    __syncthreads();
    if (threadIdx.x == 0) *flag = s;   // 0 = bf16 inputs, 1 = f32 inputs
}

// ---------------- Pass 1: pack (self-detecting dtype) ------------------------
// grid (CHB, 4): y=0..2 -> plane pack for (batch bl, channel y);
//                y=3    -> W pack (F32 only) + bias, when doW.
// bf16 mode: only even levels (transpose) are packed; odd levels read from X
// by the gemm. F32 mode: odd levels converted+packed too (Phase A).
__global__ __launch_bounds__(256)
void pack_all(const void* __restrict__ Xv, const void* __restrict__ Wv,
              const void* __restrict__ Bv,
              unsigned short* __restrict__ Gc, unsigned short* __restrict__ Wb,
              float* __restrict__ Bf, int* __restrict__ flagOut,
              int b0, int chb, int doW)
{
    __shared__ __align__(16) unsigned short lds[IMG * 128];   // 56 KB
    __shared__ int sflag;

    const int tid = threadIdx.x;

    // ---- self-detect dtype (512 samples) ----
    {
        if (tid == 0) sflag = 0;
        int bad = 0;
        const unsigned short* Wu = (const unsigned short*)Wv;
        #pragma unroll
        for (int k = tid; k < 512; k += 256) {
            unsigned v = (unsigned)Wu[2 * k] & 0x7FFFu;
            if (v >= 0x4000u) bad = 1;
        }
        __syncthreads();
        if (bad) atomicOr(&sflag, 1);
        __syncthreads();
    }
    const bool F32 = (sflag != 0);

    if (blockIdx.x == 0 && blockIdx.y == 0 && tid == 0)
        *flagOut = F32 ? 1 : 0;        // gemm (stream-later) reads this

    if (blockIdx.y == 3) {
        if (!doW) return;
        if (F32) {
            const int total = EMB * DIN / 8;            // 129024 uint4 chunks
            for (int idx = blockIdx.x * 256 + tid; idx < total; idx += chb * 256) {
                const float4* s = (const float4*)((const float*)Wv + (size_t)idx * 8);
                float4 x0 = s[0], x1 = s[1];
                uint4 o;
                o.x = pack2(x0.x, x0.y); o.y = pack2(x0.z, x0.w);
                o.z = pack2(x1.x, x1.y); o.w = pack2(x1.z, x1.w);
                ((uint4*)Wb)[idx] = o;
            }
        }
        if (blockIdx.x == 0) {
            for (int e = tid; e < EMB; e += 256)
                Bf[e] = F32 ? ((const float*)Bv)[e]
                            : bf2f(((const unsigned short*)Bv)[e]);
        }
        return;
    }

    const int bl = blockIdx.x;             // chunk-local batch
    const int c  = blockIdx.y;
    const size_t plane = ((size_t)(b0 + bl) * CIN + c) * (size_t)(IMG * IMG);
    unsigned short* Grow = Gc + (size_t)bl * NLEV * DIN + (size_t)c * 448;

    // ---- Phase A (F32 only): odd levels, streaming convert-copy ----
    if (F32) {
        const float* src = (const float*)Xv + plane + (size_t)NLEV * IMG;
        for (int v = tid; v < 3136; v += 256) {         // 3136 = 56*448/8
            const int i  = v / 56;
            const int kk = (v - i * 56) * 8;
            const float4* s = (const float4*)(src + (size_t)v * 8);
            float4 x0 = s[0], x1 = s[1];
            uint4 o;
            o.x = pack2(x0.x, x0.y); o.y = pack2(x0.z, x0.w);
            o.z = pack2(x1.x, x1.y); o.w = pack2(x1.z, x1.w);
            *(uint4*)(Grow + (size_t)(2 * i + 1) * DIN + kk) = o;
        }
    }

    // ---- Phase B load: x[b,c,0:224,0:112] -> swizzled LDS ----
    for (int v = tid; v < 3136; v += 256) {             // 3136 = 224*14
        const int r  = v / 14;
        const int vv = v - r * 14;                      // 8-elem chunk
        const int key = (r >> 3) & 15;
        uint2 o0, o1;
        if (F32) {
            const float4* s = (const float4*)((const float*)Xv + plane
                              + (size_t)r * IMG + (size_t)vv * 8);
            float4 x0 = s[0], x1 = s[1];
            o0.x = pack2(x0.x, x0.y); o0.y = pack2(x0.z, x0.w);
            o1.x = pack2(x1.x, x1.y); o1.y = pack2(x1.z, x1.w);
        } else {
            const uint2* s = (const uint2*)((const unsigned short*)Xv + plane
                              + (size_t)r * IMG + (size_t)vv * 8);
            o0 = s[0]; o1 = s[1];
        }
        *(uint2*)&lds[r * 128 + ((2 * vv)     ^ key) * 4] = o0;
        *(uint2*)&lds[r * 128 + ((2 * vv + 1) ^ key) * 4] = o1;
    }
    __syncthreads();

    // ---- Phase B store: coalesced level rows ----
    for (int idx = tid; idx < 56 * 56; idx += 256) {
        const int pr   = idx / 56;                      // column pair 0..55
        const int j    = idx - pr * 56;
        const int half = j / 28;                        // p
        const int r0   = (j - half * 28) * 8;
        const int qb   = pr >> 1;
        const int sh   = (pr & 1) * 2;
        unsigned short h[8];
        #pragma unroll
        for (int m = 0; m < 8; m++) {
            const int r = r0 + m;
            const unsigned v = *(const unsigned*)
                &lds[r * 128 + (qb ^ ((r >> 3) & 15)) * 4 + sh];
            h[m] = half ? (unsigned short)(v >> 16) : (unsigned short)(v & 0xFFFFu);
        }
        uint4 o;
        o.x = (unsigned)h[0] | ((unsigned)h[1] << 16);
        o.y = (unsigned)h[2] | ((unsigned)h[3] << 16);
        o.z = (unsigned)h[4] | ((unsigned)h[5] << 16);
        o.w = (unsigned)h[6] | ((unsigned)h[7] << 16);
        *(uint4*)(Grow + (size_t)(2 * pr) * DIN + half * IMG + r0) = o;
    }
}

// ---------------- Pass 2: 256x128 8-wave counted-vmcnt GEMM ------------------
// Out[m][n] = sum_k A[m][k]*W[n][k] + Bf[n].
// A rows: even levels from packed Gc; odd levels direct from X (bf16 mode) or
// from Gc (F32 mode). Per iter: stage(t+1, 6 loads) -> vmcnt(6) -> s_barrier
// -> ds_read+MFMA -> s_barrier. Prefetch stays in flight across barriers.
__global__ __launch_bounds__(512)
void gemm_packed(const unsigned short* __restrict__ G,
                 const unsigned short* __restrict__ Xu,
                 const unsigned short* __restrict__ Wraw,
                 const unsigned short* __restrict__ Wb,
                 const float* __restrict__ Bf,
                 float* __restrict__ Out,
                 const int* __restrict__ flag,
                 int b0)
{
    __shared__ __align__(16) unsigned short As[2][GBM * 64];   // 64 KB
    __shared__ __align__(16) unsigned short Bs[2][GBN * 64];   // 32 KB

    const int tid  = threadIdx.x;
    const int wave = tid >> 6;
    const int lane = tid & 63;
    const bool useX = (*flag == 0);          // bf16 inputs

    // bijective XCD swizzle (m204); N fast within M-panel.
    const int bid = blockIdx.x;
    const int nwg = gridDim.x;
    const int q = nwg >> 3, r = nwg & 7;
    const int xcd = bid & 7, s = bid >> 3;
    const int lid = (xcd < r ? xcd * (q + 1) : r * (q + 1) + (xcd - r) * q) + s;
    const int mT = lid / 6;                  // EMB/GBN = 6 N-tiles
    const int nT = lid - mT * 6;
    const int mBase = mT * GBM;              // chunk-local row base
    const int nBase = nT * GBN;

    const int wm   = wave >> 1, wn = wave & 1;   // 4x2 waves of 64x64
    const int lrow = lane & 15;
    const int kq   = (lane >> 4) << 3;           // 0,8,16,24
    const int swz  = (lrow & 7) << 3;            // element XOR for ds_read

    const unsigned short* Wsrc = useX ? Wraw : Wb;

    floatx4 acc[4][4];
    #pragma unroll
    for (int i = 0; i < 4; i++)
        #pragma unroll
        for (int j = 0; j < 4; j++)
            acc[i][j] = (floatx4){0.f, 0.f, 0.f, 0.f};

    // A staging: 2048 chunks (256 rows x 8); idx=(i*8+wave)*64+lane, i=0..3.
    // row=idx>>3, k8=idx&7, jc=k8^(row&7) (inverse swizzle; readers XOR same).
    // odd level & bf16: base into X; addr(t) = base + kt + c*49728, c=kt/448.
    const unsigned short* aP[4];
    int aExtra[4];
    unsigned aOff[4];
    #pragma unroll
    for (int i = 0; i < 4; i++) {
        const int idx = (i * 8 + wave) * 64 + lane;
        const int row = idx >> 3, k8 = idx & 7;
        const int jc  = k8 ^ (row & 7);
        const int m   = mBase + row;
        const int b   = m / NLEV;
        const int l   = m - b * NLEV;
        if ((l & 1) && useX) {
            aP[i] = Xu + (size_t)(b0 + b) * (CIN * IMG * IMG)
                       + (size_t)(111 + l) * IMG + jc * 8;
            aExtra[i] = 49728;               // plane step minus the 448 k-run
        } else {
            aP[i] = G + (size_t)m * DIN + jc * 8;
            aExtra[i] = 0;
        }
        aOff[i] = (unsigned)((i * 8 + wave) * 512);   // elements
    }
    // B staging: 1024 chunks (128 rows x 8); i=0..1.
    const unsigned short* bP[2];
    unsigned bOff[2];
    #pragma unroll
    for (int i = 0; i < 2; i++) {
        const int idx = (i * 8 + wave) * 64 + lane;
        const int row = idx >> 3, k8 = idx & 7;
        const int jc  = k8 ^ (row & 7);
        bP[i] = Wsrc + (size_t)(nBase + row) * DIN + jc * 8;
        bOff[i] = (unsigned)((i * 8 + wave) * 512);
    }

    // prologue: stage tile 0 into buffer 0 (6 loads in flight)
    #pragma unroll
    for (int i = 0; i < 4; i++)
        __builtin_amdgcn_global_load_lds((const AS1 void*)(aP[i]),
                                         (AS3 void*)(&As[0][0] + aOff[i]), 16, 0, 0);
    #pragma unroll
    for (int i = 0; i < 2; i++)
        __builtin_amdgcn_global_load_lds((const AS1 void*)(bP[i]),
                                         (AS3 void*)(&Bs[0][0] + bOff[i]), 16, 0, 0);

    int cur = 0;
    for (int t = 0; t < NT; ++t) {
        if (t < NT - 1) {
            const int kt = (t + 1) * 64;
            const int c  = kt / 448;                  // 0,1,2 (scalar)
            #pragma unroll
            for (int i = 0; i < 4; i++)
                __builtin_amdgcn_global_load_lds(
                    (const AS1 void*)(aP[i] + kt + c * aExtra[i]),
                    (AS3 void*)(&As[cur ^ 1][0] + aOff[i]), 16, 0, 0);
            #pragma unroll
            for (int i = 0; i < 2; i++)
                __builtin_amdgcn_global_load_lds(
                    (const AS1 void*)(bP[i] + kt),
                    (AS3 void*)(&Bs[cur ^ 1][0] + bOff[i]), 16, 0, 0);
            asm volatile("s_waitcnt vmcnt(6)" ::: "memory");   // tile-t only
        } else {
            asm volatile("s_waitcnt vmcnt(0)" ::: "memory");
        }
        __builtin_amdgcn_s_barrier();        // all waves' tile-t data landed
        __builtin_amdgcn_sched_barrier(0);

        const unsigned short* Ab = &As[cur][0];
        const unsigned short* Bb = &Bs[cur][0];
        #pragma unroll
        for (int k0 = 0; k0 < 64; k0 += 32) {
            short8 af[4], bfv[4];
            #pragma unroll
            for (int mi = 0; mi < 4; mi++)
                af[mi] = *(const short8*)&Ab[(wm * 64 + mi * 16 + lrow) * 64
                                             + ((k0 + kq) ^ swz)];
            #pragma unroll
            for (int ni = 0; ni < 4; ni++)
                bfv[ni] = *(const short8*)&Bb[(wn * 64 + ni * 16 + lrow) * 64
                                              + ((k0 + kq) ^ swz)];
            __builtin_amdgcn_s_setprio(1);
            #pragma unroll
            for (int mi = 0; mi < 4; mi++)
                #pragma unroll
                for (int ni = 0; ni < 4; ni++)
                    acc[mi][ni] = __builtin_amdgcn_mfma_f32_16x16x32_bf16(
                        af[mi], bfv[ni], acc[mi][ni], 0, 0, 0);
            __builtin_amdgcn_s_setprio(0);
        }
        __builtin_amdgcn_s_barrier();        // all waves done reading buf[cur]
        __builtin_amdgcn_sched_barrier(0);
        cur ^= 1;
    }

    // epilogue: C/D layout col=lane&15, row=(lane>>4)*4+reg (verified r5)
    const int quad = lane >> 4;
    #pragma unroll
    for (int ni = 0; ni < 4; ni++) {
        const int col = nBase + wn * 64 + ni * 16 + lrow;
        const float bv = Bf[col];
        #pragma unroll
        for (int mi = 0; mi < 4; mi++) {
            const int rbase = mBase + wm * 64 + mi * 16 + quad * 4;
            floatx4 a = acc[mi][ni];
            Out[(size_t)(rbase + 0) * EMB + col] = a[0] + bv;
            Out[(size_t)(rbase + 1) * EMB + col] = a[1] + bv;
            Out[(size_t)(rbase + 2) * EMB + col] = a[2] + bv;
            Out[(size_t)(rbase + 3) * EMB + col] = a[3] + bv;
        }
    }
}

// ---------------- Fallback: round-5 fused gather-GEMM (ws too small) ---------
template<bool F32>
__global__ __launch_bounds__(256, 2)
void lfreq_fused_gemm(const void* __restrict__ Xv,
                      const void* __restrict__ Wv,
                      const void* __restrict__ Bv,
                      const int* __restrict__ Aidx,
                      const int* __restrict__ Bidx,
                      float* __restrict__ Out,
                      const int* __restrict__ flag)
{
    if (*flag != (F32 ? 1 : 0)) return;

    __shared__ __align__(16) unsigned short As[BM][LDP];
    __shared__ __align__(16) unsigned short Bs[BN][LDP];

    const int tid   = threadIdx.x;
    const int wave  = tid >> 6;
    const int lane  = tid & 63;
    const int mBase = blockIdx.x * BM;
    const int nBase = blockIdx.y * BN;

    const int srow  = tid >> 1;
    const int shalf = tid & 1;
    const int am = mBase + srow;
    const int bb = am / NLEV;
    const int ll = am - bb * NLEV;

    floatx4 acc[4][4];
    #pragma unroll
    for (int i = 0; i < 4; i++)
        #pragma unroll
        for (int jj = 0; jj < 4; jj++)
            acc[i][jj] = (floatx4){0.f, 0.f, 0.f, 0.f};

    const int wm   = wave >> 1;
    const int wn   = wave & 1;
    const int lrow = lane & 15;
    const int kq   = (lane >> 4) << 3;

    for (int kt = 0; kt < DIN; kt += BK) {
        {
            const int koff = kt + shalf * 32;
            uint4* dst = (uint4*)&Bs[srow][shalf * 32];
            if (F32) {
                const float4* g = (const float4*)((const float*)Wv
                                + (size_t)(nBase + srow) * DIN + koff);
                #pragma unroll
                for (int q = 0; q < 4; q++) {
                    float4 v0 = g[2*q], v1 = g[2*q+1];
                    uint4 o;
                    o.x = pack2(v0.x, v0.y); o.y = pack2(v0.z, v0.w);
                    o.z = pack2(v1.x, v1.y); o.w = pack2(v1.z, v1.w);
                    dst[q] = o;
                }
            } else {
                const uint4* g = (const uint4*)((const unsigned short*)Wv
                               + (size_t)(nBase + srow) * DIN + koff);
                #pragma unroll
                for (int q = 0; q < 4; q++) dst[q] = g[q];
            }
        }
        {
            const int d0  = kt + shalf * 32;
            const int c   = (d0 >= 896) ? 2 : (d0 >= 448 ? 1 : 0);
            const int kk0 = d0 - c * 448;
            const int4* ap = (const int4*)(Aidx + ll * 448 + kk0);
            const int4* bp = (const int4*)(Bidx + ll * 448 + kk0);
            unsigned* du = (unsigned*)&As[srow][shalf * 32];
            if (F32) {
                const float* plane = (const float*)Xv
                    + (size_t)bb * (CIN * IMG * IMG) + (size_t)c * (IMG * IMG);
                #pragma unroll
                for (int q = 0; q < 8; q++) {
                    int4 av = ap[q], bv = bp[q];
                    du[2*q+0] = pack2(plane[av.x * IMG + bv.x], plane[av.y * IMG + bv.y]);
                    du[2*q+1] = pack2(plane[av.z * IMG + bv.z], plane[av.w * IMG + bv.w]);
                }
            } else {
                const unsigned short* plane = (const unsigned short*)Xv
                    + (size_t)bb * (CIN * IMG * IMG) + (size_t)c * (IMG * IMG);
                #pragma unroll
                for (int q = 0; q < 8; q++) {
                    int4 av = ap[q], bv = bp[q];
                    unsigned e0 = plane[av.x * IMG + bv.x];
                    unsigned e1 = plane[av.y * IMG + bv.y];
                    unsigned e2 = plane[av.z * IMG + bv.z];
                    unsigned e3 = plane[av.w * IMG + bv.w];
                    du[2*q+0] = e0 | (e1 << 16);
                    du[2*q+1] = e2 | (e3 << 16);
                }
            }
        }
        __syncthreads();

        #pragma unroll
        for (int k0 = 0; k0 < BK; k0 += 32) {
            short8 af[4], bfv[4];
            #pragma unroll
            for (int mi = 0; mi < 4; mi++)
                af[mi] = *(const short8*)&As[wm*64 + mi*16 + lrow][k0 + kq];
            #pragma unroll
            for (int ni = 0; ni < 4; ni++)
                bfv[ni] = *(const short8*)&Bs[wn*64 + ni*16 + lrow][k0 + kq];
            #pragma unroll
            for (int mi = 0; mi < 4; mi++)
                #pragma unroll
                for (int ni = 0; ni < 4; ni++)
                    acc[mi][ni] = __builtin_amdgcn_mfma_f32_16x16x32_bf16(
                        af[mi], bfv[ni], acc[mi][ni], 0, 0, 0);
        }
        __syncthreads();
    }

    const int quad = lane >> 4;
    #pragma unroll
    for (int ni = 0; ni < 4; ni++) {
        const int col = nBase + wn*64 + ni*16 + lrow;
        const float bv = F32 ? ((const float*)Bv)[col]
                             : bf2f(((const unsigned short*)Bv)[col]);
        #pragma unroll
        for (int mi = 0; mi < 4; mi++) {
            const int rbase = mBase + wm*64 + mi*16 + quad*4;
            floatx4 a = acc[mi][ni];
            Out[(size_t)(rbase+0)*EMB + col] = a[0] + bv;
            Out[(size_t)(rbase+1)*EMB + col] = a[1] + bv;
            Out[(size_t)(rbase+2)*EMB + col] = a[2] + bv;
            Out[(size_t)(rbase+3)*EMB + col] = a[3] + bv;
        }
    }
}

extern "C" void kernel_launch(void* const* d_in, const int* in_sizes, int n_in,
                              void* d_out, int out_size, void* d_ws, size_t ws_size,
                              hipStream_t stream) {
    const void* X    = d_in[0];              // x: [256,3,224,224]
    const void* Wt   = d_in[1];              // W: [768,1344]
    const void* Bias = d_in[2];              // b: [768]
    const int*  Ai   = (const int*)d_in[3];  // a_idx (unused in packed path)
    const int*  Bi   = (const int*)d_in[4];  // b_idx
    float* Out = (float*)d_out;              // f32 [256,112,768]

    char* ws  = (char*)d_ws;
    int* flag = (int*)ws;

    // workspace layout: [0] flag | [256] Bf f32[768] | [4096] Wb bf16[768*1344]
    //                   | [gOff] G chunk bf16[CHB*112*1344]
    float* Bf          = (float*)(ws + 256);
    unsigned short* Wb = (unsigned short*)(ws + 4096);
    const size_t gOff  = 4096 + (size_t)EMB * DIN * 2;        // 2,068,480
    unsigned short* Gc = (unsigned short*)(ws + gOff);

    int CHB = 0;
    const int cand[5] = {256, 128, 64, 32, 16};     // *112 divisible by 256
    for (int t = 0; t < 5; t++) {
        if (gOff + (size_t)cand[t] * NLEV * DIN * 2 <= ws_size) { CHB = cand[t]; break; }
    }

    if (CHB == 0) {
        detect_dtype<<<dim3(1), dim3(256), 0, stream>>>((const unsigned short*)Wt, flag);
        dim3 grid(MTOT / BM, EMB / BN);
        lfreq_fused_gemm<false><<<grid, dim3(256), 0, stream>>>(X, Wt, Bias, Ai, Bi, Out, flag);
        lfreq_fused_gemm<true ><<<grid, dim3(256), 0, stream>>>(X, Wt, Bias, Ai, Bi, Out, flag);
        return;
    }

    for (int b0 = 0; b0 < BATCH; b0 += CHB) {
        dim3 pgrid(CHB, 4);
        pack_all<<<pgrid, dim3(256), 0, stream>>>(X, Wt, Bias, Gc, Wb, Bf, flag,
                                                  b0, CHB, b0 == 0 ? 1 : 0);
        dim3 ggrid(CHB * NLEV / GBM * 6);   // 1-D swizzled grid
        gemm_packed<<<ggrid, dim3(512), 0, stream>>>(
            Gc, (const unsigned short*)X, (const unsigned short*)Wt, Wb, Bf,
            Out + (size_t)b0 * NLEV * EMB, flag, b0);
    }
}

// Round 6
// 344.145 us; speedup vs baseline: 1.0309x; 1.0309x over previous
//
#include <hip/hip_runtime.h>
#include <stdint.h>

// LFreqEmbed — ROUND 11: back to 128², single-buffer + max block-TLP.
// Round-10 post-mortem: 256x128 tile (96KB LDS -> 1 block/CU) regressed gemm
// to 106us exactly per the pre-committed failure criterion: depth-2 prefetch
// covers ~300cyc of ~600-900cyc latency and with 1 block/CU nothing hides the
// residue. m97 evidence: 32KB single-buffered 128² at ~5 blocks/CU reaches
// 912 TF via block-level TLP. This round: 128²/BK=64, single 32KB buffer,
// plain __syncthreads, keep T2 swizzle (conflicts 0) + XCD swizzle + odd-rows
// direct-from-X; drop setprio (m190: negative on non-phase-split GEMM).

#define IMG   224
#define NLEV  112
#define CIN   3
#define DIN   1344
#define EMB   768
#define BATCH 256
#define MTOT  28672
#define NT    21          // DIN/64 K-steps

// fallback (round-5 fused kernel) tile params
#define BM    128
#define BN    128
#define BK    64
#define LDP   72

#define AS1 __attribute__((address_space(1)))
#define AS3 __attribute__((address_space(3)))

typedef __attribute__((ext_vector_type(8))) short   short8;
typedef __attribute__((ext_vector_type(4))) float   floatx4;

__device__ __forceinline__ unsigned short f2bf(float f) {
    unsigned u = __float_as_uint(f);
    unsigned r = (u + 0x7fffu + ((u >> 16) & 1u)) >> 16;
    return (unsigned short)r;
}
__device__ __forceinline__ float bf2f(unsigned short s) {
    return __uint_as_float(((unsigned)s) << 16);
}
__device__ __forceinline__ unsigned pack2(float a, float b) {
    return (unsigned)f2bf(a) | ((unsigned)f2bf(b) << 16);
}

// dtype probe (fallback path): bf16 inputs -> W[2k] real weights (<0x4000);
// f32 inputs -> mantissa halves (uniform bits).
__global__ void detect_dtype(const unsigned short* __restrict__ W, int* flag) {
    __shared__ int s;
    if (threadIdx.x == 0) s = 0;
    __syncthreads();
    int bad = 0;
    for (int k = threadIdx.x; k < 4096; k += 256) {
        unsigned v = (unsigned)W[2 * k] & 0x7FFFu;
        if (v >= 0x4000u) bad = 1;
    }
    if (bad) atomicOr(&s, 1);
    __syncthreads();
    if (threadIdx.x == 0) *flag = s;   // 0 = bf16 inputs, 1 = f32 inputs
}

// ---------------- Pass 1: pack (self-detecting dtype) ------------------------
// grid (CHB, 4): y=0..2 -> plane pack for (batch bl, channel y);
//                y=3    -> W pack (F32 only) + bias, when doW.
// bf16 mode: only even levels (transpose) are packed; odd levels read from X
// by the gemm. F32 mode: odd levels converted+packed too (Phase A).
__global__ __launch_bounds__(256)
void pack_all(const void* __restrict__ Xv, const void* __restrict__ Wv,
              const void* __restrict__ Bv,
              unsigned short* __restrict__ Gc, unsigned short* __restrict__ Wb,
              float* __restrict__ Bf, int* __restrict__ flagOut,
              int b0, int chb, int doW)
{
    __shared__ __align__(16) unsigned short lds[IMG * 128];   // 56 KB
    __shared__ int sflag;

    const int tid = threadIdx.x;

    // ---- self-detect dtype (512 samples) ----
    {
        if (tid == 0) sflag = 0;
        int bad = 0;
        const unsigned short* Wu = (const unsigned short*)Wv;
        #pragma unroll
        for (int k = tid; k < 512; k += 256) {
            unsigned v = (unsigned)Wu[2 * k] & 0x7FFFu;
            if (v >= 0x4000u) bad = 1;
        }
        __syncthreads();
        if (bad) atomicOr(&sflag, 1);
        __syncthreads();
    }
    const bool F32 = (sflag != 0);

    if (blockIdx.x == 0 && blockIdx.y == 0 && tid == 0)
        *flagOut = F32 ? 1 : 0;        // gemm (stream-later) reads this

    if (blockIdx.y == 3) {
        if (!doW) return;
        if (F32) {
            const int total = EMB * DIN / 8;            // 129024 uint4 chunks
            for (int idx = blockIdx.x * 256 + tid; idx < total; idx += chb * 256) {
                const float4* s = (const float4*)((const float*)Wv + (size_t)idx * 8);
                float4 x0 = s[0], x1 = s[1];
                uint4 o;
                o.x = pack2(x0.x, x0.y); o.y = pack2(x0.z, x0.w);
                o.z = pack2(x1.x, x1.y); o.w = pack2(x1.z, x1.w);
                ((uint4*)Wb)[idx] = o;
            }
        }
        if (blockIdx.x == 0) {
            for (int e = tid; e < EMB; e += 256)
                Bf[e] = F32 ? ((const float*)Bv)[e]
                            : bf2f(((const unsigned short*)Bv)[e]);
        }
        return;
    }

    const int bl = blockIdx.x;             // chunk-local batch
    const int c  = blockIdx.y;
    const size_t plane = ((size_t)(b0 + bl) * CIN + c) * (size_t)(IMG * IMG);
    unsigned short* Grow = Gc + (size_t)bl * NLEV * DIN + (size_t)c * 448;

    // ---- Phase A (F32 only): odd levels, streaming convert-copy ----
    if (F32) {
        const float* src = (const float*)Xv + plane + (size_t)NLEV * IMG;
        for (int v = tid; v < 3136; v += 256) {         // 3136 = 56*448/8
            const int i  = v / 56;
            const int kk = (v - i * 56) * 8;
            const float4* s = (const float4*)(src + (size_t)v * 8);
            float4 x0 = s[0], x1 = s[1];
            uint4 o;
            o.x = pack2(x0.x, x0.y); o.y = pack2(x0.z, x0.w);
            o.z = pack2(x1.x, x1.y); o.w = pack2(x1.z, x1.w);
            *(uint4*)(Grow + (size_t)(2 * i + 1) * DIN + kk) = o;
        }
    }

    // ---- Phase B load: x[b,c,0:224,0:112] -> swizzled LDS ----
    for (int v = tid; v < 3136; v += 256) {             // 3136 = 224*14
        const int r  = v / 14;
        const int vv = v - r * 14;                      // 8-elem chunk
        const int key = (r >> 3) & 15;
        uint2 o0, o1;
        if (F32) {
            const float4* s = (const float4*)((const float*)Xv + plane
                              + (size_t)r * IMG + (size_t)vv * 8);
            float4 x0 = s[0], x1 = s[1];
            o0.x = pack2(x0.x, x0.y); o0.y = pack2(x0.z, x0.w);
            o1.x = pack2(x1.x, x1.y); o1.y = pack2(x1.z, x1.w);
        } else {
            const uint2* s = (const uint2*)((const unsigned short*)Xv + plane
                              + (size_t)r * IMG + (size_t)vv * 8);
            o0 = s[0]; o1 = s[1];
        }
        *(uint2*)&lds[r * 128 + ((2 * vv)     ^ key) * 4] = o0;
        *(uint2*)&lds[r * 128 + ((2 * vv + 1) ^ key) * 4] = o1;
    }
    __syncthreads();

    // ---- Phase B store: coalesced level rows ----
    for (int idx = tid; idx < 56 * 56; idx += 256) {
        const int pr   = idx / 56;                      // column pair 0..55
        const int j    = idx - pr * 56;
        const int half = j / 28;                        // p
        const int r0   = (j - half * 28) * 8;
        const int qb   = pr >> 1;
        const int sh   = (pr & 1) * 2;
        unsigned short h[8];
        #pragma unroll
        for (int m = 0; m < 8; m++) {
            const int r = r0 + m;
            const unsigned v = *(const unsigned*)
                &lds[r * 128 + (qb ^ ((r >> 3) & 15)) * 4 + sh];
            h[m] = half ? (unsigned short)(v >> 16) : (unsigned short)(v & 0xFFFFu);
        }
        uint4 o;
        o.x = (unsigned)h[0] | ((unsigned)h[1] << 16);
        o.y = (unsigned)h[2] | ((unsigned)h[3] << 16);
        o.z = (unsigned)h[4] | ((unsigned)h[5] << 16);
        o.w = (unsigned)h[6] | ((unsigned)h[7] << 16);
        *(uint4*)(Grow + (size_t)(2 * pr) * DIN + half * IMG + r0) = o;
    }
}

// ---------------- Pass 2: 128x128 single-buffer TLP GEMM ---------------------
// Out[m][n] = sum_k A[m][k]*W[n][k] + Bf[n]. 32KB LDS -> ~5 blocks/CU; other
// blocks' MFMA hides each block's stage-drain (m97 mechanism, 912 TF).
// A rows: even levels from packed Gc; odd levels direct from X (bf16 mode).
__global__ __launch_bounds__(256)
void gemm_packed(const unsigned short* __restrict__ G,
                 const unsigned short* __restrict__ Xu,
                 const unsigned short* __restrict__ Wraw,
                 const unsigned short* __restrict__ Wb,
                 const float* __restrict__ Bf,
                 float* __restrict__ Out,
                 const int* __restrict__ flag,
                 int b0)
{
    __shared__ __align__(16) unsigned short As[128 * 64];   // 16 KB
    __shared__ __align__(16) unsigned short Bs[128 * 64];   // 16 KB

    const int tid  = threadIdx.x;
    const int wave = tid >> 6;
    const int lane = tid & 63;
    const bool useX = (*flag == 0);          // bf16 inputs

    // bijective XCD swizzle (m204); N fast within M-panel.
    const int bid = blockIdx.x;
    const int nwg = gridDim.x;
    const int q = nwg >> 3, r = nwg & 7;
    const int xcd = bid & 7, s = bid >> 3;
    const int lid = (xcd < r ? xcd * (q + 1) : r * (q + 1) + (xcd - r) * q) + s;
    const int mT = lid / 6;                  // EMB/128 = 6 N-tiles
    const int nT = lid - mT * 6;
    const int mBase = mT * 128;              // chunk-local row base
    const int nBase = nT * 128;

    const int wm   = wave >> 1, wn = wave & 1;   // 2x2 waves of 64x64
    const int lrow = lane & 15;
    const int kq   = (lane >> 4) << 3;           // 0,8,16,24
    const int swz  = (lrow & 7) << 3;            // element XOR for ds_read

    const unsigned short* Wsrc = useX ? Wraw : Wb;

    floatx4 acc[4][4];
    #pragma unroll
    for (int i = 0; i < 4; i++)
        #pragma unroll
        for (int j = 0; j < 4; j++)
            acc[i][j] = (floatx4){0.f, 0.f, 0.f, 0.f};

    // staging map: idx=(i*4+wave)*64+lane; row=idx>>3, k8=idx&7.
    // linear LDS dest; inverse-swizzled global source chunk jc = k8 ^ (row&7).
    // odd level & bf16: base into X (odd rows are contiguous runs of X:
    // addr = (b0+b)*150528 + (111+l)*224 + k, channel step += 49728).
    const unsigned short* aP[4];
    int aExtra[4];
    unsigned aOff[4];
    #pragma unroll
    for (int i = 0; i < 4; i++) {
        const int idx = (i * 4 + wave) * 64 + lane;
        const int row = idx >> 3, k8 = idx & 7;
        const int jc  = k8 ^ (row & 7);
        const int m   = mBase + row;
        const int b   = m / NLEV;
        const int l   = m - b * NLEV;
        if ((l & 1) && useX) {
            aP[i] = Xu + (size_t)(b0 + b) * (CIN * IMG * IMG)
                       + (size_t)(111 + l) * IMG + jc * 8;
            aExtra[i] = 49728;               // plane step minus the 448 k-run
        } else {
            aP[i] = G + (size_t)m * DIN + jc * 8;
            aExtra[i] = 0;
        }
        aOff[i] = (unsigned)((i * 4 + wave) * 512);   // elements
    }
    const unsigned short* bP[4];
    unsigned bOff[4];
    #pragma unroll
    for (int i = 0; i < 4; i++) {
        const int idx = (i * 4 + wave) * 64 + lane;
        const int row = idx >> 3, k8 = idx & 7;
        const int jc  = k8 ^ (row & 7);
        bP[i] = Wsrc + (size_t)(nBase + row) * DIN + jc * 8;
        bOff[i] = (unsigned)((i * 4 + wave) * 512);
    }

    for (int t = 0; t < NT; ++t) {
        const int kt = t * 64;
        const int c  = kt / 448;             // 0,1,2 (scalar, const divisor)
        #pragma unroll
        for (int i = 0; i < 4; i++) {
            __builtin_amdgcn_global_load_lds(
                (const AS1 void*)(aP[i] + kt + c * aExtra[i]),
                (AS3 void*)(As + aOff[i]), 16, 0, 0);
            __builtin_amdgcn_global_load_lds(
                (const AS1 void*)(bP[i] + kt),
                (AS3 void*)(Bs + bOff[i]), 16, 0, 0);
        }
        __syncthreads();   // drains own vmcnt -> all staging visible

        #pragma unroll
        for (int k0 = 0; k0 < 64; k0 += 32) {
            short8 af[4], bfv[4];
            #pragma unroll
            for (int mi = 0; mi < 4; mi++)
                af[mi] = *(const short8*)&As[(wm * 64 + mi * 16 + lrow) * 64
                                             + ((k0 + kq) ^ swz)];
            #pragma unroll
            for (int ni = 0; ni < 4; ni++)
                bfv[ni] = *(const short8*)&Bs[(wn * 64 + ni * 16 + lrow) * 64
                                              + ((k0 + kq) ^ swz)];
            #pragma unroll
            for (int mi = 0; mi < 4; mi++)
                #pragma unroll
                for (int ni = 0; ni < 4; ni++)
                    acc[mi][ni] = __builtin_amdgcn_mfma_f32_16x16x32_bf16(
                        af[mi], bfv[ni], acc[mi][ni], 0, 0, 0);
        }
        __syncthreads();   // all waves done reading before next overwrite
    }

    // epilogue: C/D layout col=lane&15, row=(lane>>4)*4+reg (verified r5)
    const int quad = lane >> 4;
    #pragma unroll
    for (int ni = 0; ni < 4; ni++) {
        const int col = nBase + wn * 64 + ni * 16 + lrow;
        const float bv = Bf[col];
        #pragma unroll
        for (int mi = 0; mi < 4; mi++) {
            const int rbase = mBase + wm * 64 + mi * 16 + quad * 4;
            floatx4 a = acc[mi][ni];
            Out[(size_t)(rbase + 0) * EMB + col] = a[0] + bv;
            Out[(size_t)(rbase + 1) * EMB + col] = a[1] + bv;
            Out[(size_t)(rbase + 2) * EMB + col] = a[2] + bv;
            Out[(size_t)(rbase + 3) * EMB + col] = a[3] + bv;
        }
    }
}

// ---------------- Fallback: round-5 fused gather-GEMM (ws too small) ---------
template<bool F32>
__global__ __launch_bounds__(256, 2)
void lfreq_fused_gemm(const void* __restrict__ Xv,
                      const void* __restrict__ Wv,
                      const void* __restrict__ Bv,
                      const int* __restrict__ Aidx,
                      const int* __restrict__ Bidx,
                      float* __restrict__ Out,
                      const int* __restrict__ flag)
{
    if (*flag != (F32 ? 1 : 0)) return;

    __shared__ __align__(16) unsigned short As[BM][LDP];
    __shared__ __align__(16) unsigned short Bs[BN][LDP];

    const int tid   = threadIdx.x;
    const int wave  = tid >> 6;
    const int lane  = tid & 63;
    const int mBase = blockIdx.x * BM;
    const int nBase = blockIdx.y * BN;

    const int srow  = tid >> 1;
    const int shalf = tid & 1;
    const int am = mBase + srow;
    const int bb = am / NLEV;
    const int ll = am - bb * NLEV;

    floatx4 acc[4][4];
    #pragma unroll
    for (int i = 0; i < 4; i++)
        #pragma unroll
        for (int jj = 0; jj < 4; jj++)
            acc[i][jj] = (floatx4){0.f, 0.f, 0.f, 0.f};

    const int wm   = wave >> 1;
    const int wn   = wave & 1;
    const int lrow = lane & 15;
    const int kq   = (lane >> 4) << 3;

    for (int kt = 0; kt < DIN; kt += BK) {
        {
            const int koff = kt + shalf * 32;
            uint4* dst = (uint4*)&Bs[srow][shalf * 32];
            if (F32) {
                const float4* g = (const float4*)((const float*)Wv
                                + (size_t)(nBase + srow) * DIN + koff);
                #pragma unroll
                for (int q = 0; q < 4; q++) {
                    float4 v0 = g[2*q], v1 = g[2*q+1];
                    uint4 o;
                    o.x = pack2(v0.x, v0.y); o.y = pack2(v0.z, v0.w);
                    o.z = pack2(v1.x, v1.y); o.w = pack2(v1.z, v1.w);
                    dst[q] = o;
                }
            } else {
                const uint4* g = (const uint4*)((const unsigned short*)Wv
                               + (size_t)(nBase + srow) * DIN + koff);
                #pragma unroll
                for (int q = 0; q < 4; q++) dst[q] = g[q];
            }
        }
        {
            const int d0  = kt + shalf * 32;
            const int c   = (d0 >= 896) ? 2 : (d0 >= 448 ? 1 : 0);
            const int kk0 = d0 - c * 448;
            const int4* ap = (const int4*)(Aidx + ll * 448 + kk0);
            const int4* bp = (const int4*)(Bidx + ll * 448 + kk0);
            unsigned* du = (unsigned*)&As[srow][shalf * 32];
            if (F32) {
                const float* plane = (const float*)Xv
                    + (size_t)bb * (CIN * IMG * IMG) + (size_t)c * (IMG * IMG);
                #pragma unroll
                for (int q = 0; q < 8; q++) {
                    int4 av = ap[q], bv = bp[q];
                    du[2*q+0] = pack2(plane[av.x * IMG + bv.x], plane[av.y * IMG + bv.y]);
                    du[2*q+1] = pack2(plane[av.z * IMG + bv.z], plane[av.w * IMG + bv.w]);
                }
            } else {
                const unsigned short* plane = (const unsigned short*)Xv
                    + (size_t)bb * (CIN * IMG * IMG) + (size_t)c * (IMG * IMG);
                #pragma unroll
                for (int q = 0; q < 8; q++) {
                    int4 av = ap[q], bv = bp[q];
                    unsigned e0 = plane[av.x * IMG + bv.x];
                    unsigned e1 = plane[av.y * IMG + bv.y];
                    unsigned e2 = plane[av.z * IMG + bv.z];
                    unsigned e3 = plane[av.w * IMG + bv.w];
                    du[2*q+0] = e0 | (e1 << 16);
                    du[2*q+1] = e2 | (e3 << 16);
                }
            }
        }
        __syncthreads();

        #pragma unroll
        for (int k0 = 0; k0 < BK; k0 += 32) {
            short8 af[4], bfv[4];
            #pragma unroll
            for (int mi = 0; mi < 4; mi++)
                af[mi] = *(const short8*)&As[wm*64 + mi*16 + lrow][k0 + kq];
            #pragma unroll
            for (int ni = 0; ni < 4; ni++)
                bfv[ni] = *(const short8*)&Bs[wn*64 + ni*16 + lrow][k0 + kq];
            #pragma unroll
            for (int mi = 0; mi < 4; mi++)
                #pragma unroll
                for (int ni = 0; ni < 4; ni++)
                    acc[mi][ni] = __builtin_amdgcn_mfma_f32_16x16x32_bf16(
                        af[mi], bfv[ni], acc[mi][ni], 0, 0, 0);
        }
        __syncthreads();
    }

    const int quad = lane >> 4;
    #pragma unroll
    for (int ni = 0; ni < 4; ni++) {
        const int col = nBase + wn*64 + ni*16 + lrow;
        const float bv = F32 ? ((const float*)Bv)[col]
                             : bf2f(((const unsigned short*)Bv)[col]);
        #pragma unroll
        for (int mi = 0; mi < 4; mi++) {
            const int rbase = mBase + wm*64 + mi*16 + quad*4;
            floatx4 a = acc[mi][ni];
            Out[(size_t)(rbase+0)*EMB + col] = a[0] + bv;
            Out[(size_t)(rbase+1)*EMB + col] = a[1] + bv;
            Out[(size_t)(rbase+2)*EMB + col] = a[2] + bv;
            Out[(size_t)(rbase+3)*EMB + col] = a[3] + bv;
        }
    }
}

extern "C" void kernel_launch(void* const* d_in, const int* in_sizes, int n_in,
                              void* d_out, int out_size, void* d_ws, size_t ws_size,
                              hipStream_t stream) {
    const void* X    = d_in[0];              // x: [256,3,224,224]
    const void* Wt   = d_in[1];              // W: [768,1344]
    const void* Bias = d_in[2];              // b: [768]
    const int*  Ai   = (const int*)d_in[3];  // a_idx (unused in packed path)
    const int*  Bi   = (const int*)d_in[4];  // b_idx
    float* Out = (float*)d_out;              // f32 [256,112,768]

    char* ws  = (char*)d_ws;
    int* flag = (int*)ws;

    // workspace layout: [0] flag | [256] Bf f32[768] | [4096] Wb bf16[768*1344]
    //                   | [gOff] G chunk bf16[CHB*112*1344]
    float* Bf          = (float*)(ws + 256);
    unsigned short* Wb = (unsigned short*)(ws + 4096);
    const size_t gOff  = 4096 + (size_t)EMB * DIN * 2;        // 2,068,480
    unsigned short* Gc = (unsigned short*)(ws + gOff);

    int CHB = 0;
    const int cand[6] = {256, 128, 64, 32, 16, 8};   // *112 divisible by 128
    for (int t = 0; t < 6; t++) {
        if (gOff + (size_t)cand[t] * NLEV * DIN * 2 <= ws_size) { CHB = cand[t]; break; }
    }

    if (CHB == 0) {
        detect_dtype<<<dim3(1), dim3(256), 0, stream>>>((const unsigned short*)Wt, flag);
        dim3 grid(MTOT / BM, EMB / BN);
        lfreq_fused_gemm<false><<<grid, dim3(256), 0, stream>>>(X, Wt, Bias, Ai, Bi, Out, flag);
        lfreq_fused_gemm<true ><<<grid, dim3(256), 0, stream>>>(X, Wt, Bias, Ai, Bi, Out, flag);
        return;
    }

    for (int b0 = 0; b0 < BATCH; b0 += CHB) {
        dim3 pgrid(CHB, 4);
        pack_all<<<pgrid, dim3(256), 0, stream>>>(X, Wt, Bias, Gc, Wb, Bf, flag,
                                                  b0, CHB, b0 == 0 ? 1 : 0);
        dim3 ggrid(CHB * NLEV / 128 * 6);   // 1-D swizzled grid
        gemm_packed<<<ggrid, dim3(256), 0, stream>>>(
            Gc, (const unsigned short*)X, (const unsigned short*)Wt, Wb, Bf,
            Out + (size_t)b0 * NLEV * EMB, flag, b0);
    }
}

// Round 7
// 337.457 us; speedup vs baseline: 1.0513x; 1.0198x over previous
//
#include <hip/hip_runtime.h>
#include <stdint.h>

// LFreqEmbed — ROUND 12: best-of composition (r9 gemm + r11 pack/staging).
// Round-11 post-mortem: single-buffer TLP hypothesis FAILED (105us ≈ r10's
// 106; occupancy ~19% invariant across LDS 32/64/96KB). Cross-round ranking:
// r9 counted-vmcnt dbuf 128² is best (<92us). This round restores r9's gemm
// EXACTLY and keeps r11's odd-levels-direct-from-X (proven correct, halves
// pack work). No new mechanisms.

#define IMG   224
#define NLEV  112
#define CIN   3
#define DIN   1344
#define EMB   768
#define BATCH 256
#define MTOT  28672
#define NT    21          // DIN/64 K-steps

// fallback (round-5 fused kernel) tile params
#define BM    128
#define BN    128
#define BK    64
#define LDP   72

#define AS1 __attribute__((address_space(1)))
#define AS3 __attribute__((address_space(3)))

typedef __attribute__((ext_vector_type(8))) short   short8;
typedef __attribute__((ext_vector_type(4))) float   floatx4;

__device__ __forceinline__ unsigned short f2bf(float f) {
    unsigned u = __float_as_uint(f);
    unsigned r = (u + 0x7fffu + ((u >> 16) & 1u)) >> 16;
    return (unsigned short)r;
}
__device__ __forceinline__ float bf2f(unsigned short s) {
    return __uint_as_float(((unsigned)s) << 16);
}
__device__ __forceinline__ unsigned pack2(float a, float b) {
    return (unsigned)f2bf(a) | ((unsigned)f2bf(b) << 16);
}

// dtype probe (fallback path): bf16 inputs -> W[2k] real weights (<0x4000);
// f32 inputs -> mantissa halves (uniform bits).
__global__ void detect_dtype(const unsigned short* __restrict__ W, int* flag) {
    __shared__ int s;
    if (threadIdx.x == 0) s = 0;
    __syncthreads();
    int bad = 0;
    for (int k = threadIdx.x; k < 4096; k += 256) {
        unsigned v = (unsigned)W[2 * k] & 0x7FFFu;
        if (v >= 0x4000u) bad = 1;
    }
    if (bad) atomicOr(&s, 1);
    __syncthreads();
    if (threadIdx.x == 0) *flag = s;   // 0 = bf16 inputs, 1 = f32 inputs
}

// ---------------- Pass 1: pack (self-detecting dtype) ------------------------
// grid (CHB, 4): y=0..2 -> plane pack for (batch bl, channel y);
//                y=3    -> W pack (F32 only) + bias, when doW.
// bf16 mode: only even levels (transpose) are packed; odd levels read from X
// by the gemm. F32 mode: odd levels converted+packed too (Phase A).
__global__ __launch_bounds__(256)
void pack_all(const void* __restrict__ Xv, const void* __restrict__ Wv,
              const void* __restrict__ Bv,
              unsigned short* __restrict__ Gc, unsigned short* __restrict__ Wb,
              float* __restrict__ Bf, int* __restrict__ flagOut,
              int b0, int chb, int doW)
{
    __shared__ __align__(16) unsigned short lds[IMG * 128];   // 56 KB
    __shared__ int sflag;

    const int tid = threadIdx.x;

    // ---- self-detect dtype (512 samples) ----
    {
        if (tid == 0) sflag = 0;
        int bad = 0;
        const unsigned short* Wu = (const unsigned short*)Wv;
        #pragma unroll
        for (int k = tid; k < 512; k += 256) {
            unsigned v = (unsigned)Wu[2 * k] & 0x7FFFu;
            if (v >= 0x4000u) bad = 1;
        }
        __syncthreads();
        if (bad) atomicOr(&sflag, 1);
        __syncthreads();
    }
    const bool F32 = (sflag != 0);

    if (blockIdx.x == 0 && blockIdx.y == 0 && tid == 0)
        *flagOut = F32 ? 1 : 0;        // gemm (stream-later) reads this

    if (blockIdx.y == 3) {
        if (!doW) return;
        if (F32) {
            const int total = EMB * DIN / 8;            // 129024 uint4 chunks
            for (int idx = blockIdx.x * 256 + tid; idx < total; idx += chb * 256) {
                const float4* s = (const float4*)((const float*)Wv + (size_t)idx * 8);
                float4 x0 = s[0], x1 = s[1];
                uint4 o;
                o.x = pack2(x0.x, x0.y); o.y = pack2(x0.z, x0.w);
                o.z = pack2(x1.x, x1.y); o.w = pack2(x1.z, x1.w);
                ((uint4*)Wb)[idx] = o;
            }
        }
        if (blockIdx.x == 0) {
            for (int e = tid; e < EMB; e += 256)
                Bf[e] = F32 ? ((const float*)Bv)[e]
                            : bf2f(((const unsigned short*)Bv)[e]);
        }
        return;
    }

    const int bl = blockIdx.x;             // chunk-local batch
    const int c  = blockIdx.y;
    const size_t plane = ((size_t)(b0 + bl) * CIN + c) * (size_t)(IMG * IMG);
    unsigned short* Grow = Gc + (size_t)bl * NLEV * DIN + (size_t)c * 448;

    // ---- Phase A (F32 only): odd levels, streaming convert-copy ----
    if (F32) {
        const float* src = (const float*)Xv + plane + (size_t)NLEV * IMG;
        for (int v = tid; v < 3136; v += 256) {         // 3136 = 56*448/8
            const int i  = v / 56;
            const int kk = (v - i * 56) * 8;
            const float4* s = (const float4*)(src + (size_t)v * 8);
            float4 x0 = s[0], x1 = s[1];
            uint4 o;
            o.x = pack2(x0.x, x0.y); o.y = pack2(x0.z, x0.w);
            o.z = pack2(x1.x, x1.y); o.w = pack2(x1.z, x1.w);
            *(uint4*)(Grow + (size_t)(2 * i + 1) * DIN + kk) = o;
        }
    }

    // ---- Phase B load: x[b,c,0:224,0:112] -> swizzled LDS ----
    for (int v = tid; v < 3136; v += 256) {             // 3136 = 224*14
        const int r  = v / 14;
        const int vv = v - r * 14;                      // 8-elem chunk
        const int key = (r >> 3) & 15;
        uint2 o0, o1;
        if (F32) {
            const float4* s = (const float4*)((const float*)Xv + plane
                              + (size_t)r * IMG + (size_t)vv * 8);
            float4 x0 = s[0], x1 = s[1];
            o0.x = pack2(x0.x, x0.y); o0.y = pack2(x0.z, x0.w);
            o1.x = pack2(x1.x, x1.y); o1.y = pack2(x1.z, x1.w);
        } else {
            const uint2* s = (const uint2*)((const unsigned short*)Xv + plane
                              + (size_t)r * IMG + (size_t)vv * 8);
            o0 = s[0]; o1 = s[1];
        }
        *(uint2*)&lds[r * 128 + ((2 * vv)     ^ key) * 4] = o0;
        *(uint2*)&lds[r * 128 + ((2 * vv + 1) ^ key) * 4] = o1;
    }
    __syncthreads();

    // ---- Phase B store: coalesced level rows ----
    for (int idx = tid; idx < 56 * 56; idx += 256) {
        const int pr   = idx / 56;                      // column pair 0..55
        const int j    = idx - pr * 56;
        const int half = j / 28;                        // p
        const int r0   = (j - half * 28) * 8;
        const int qb   = pr >> 1;
        const int sh   = (pr & 1) * 2;
        unsigned short h[8];
        #pragma unroll
        for (int m = 0; m < 8; m++) {
            const int r = r0 + m;
            const unsigned v = *(const unsigned*)
                &lds[r * 128 + (qb ^ ((r >> 3) & 15)) * 4 + sh];
            h[m] = half ? (unsigned short)(v >> 16) : (unsigned short)(v & 0xFFFFu);
        }
        uint4 o;
        o.x = (unsigned)h[0] | ((unsigned)h[1] << 16);
        o.y = (unsigned)h[2] | ((unsigned)h[3] << 16);
        o.z = (unsigned)h[4] | ((unsigned)h[5] << 16);
        o.w = (unsigned)h[6] | ((unsigned)h[7] << 16);
        *(uint4*)(Grow + (size_t)(2 * pr) * DIN + half * IMG + r0) = o;
    }
}

// ---------------- Pass 2: counted-vmcnt dbuf GEMM (r9 structure) -------------
// Out[m][n] = sum_k A[m][k]*W[n][k] + Bf[n]; 128x128 tile, BK=64, 4 waves.
// Per iter: stage(t+1, 8 loads) -> vmcnt(8) [tile-t only] -> s_barrier ->
// ds_read+MFMA (setprio) -> s_barrier. Prefetch flies across both barriers.
// A rows: even levels from packed Gc; odd levels direct from X (bf16 mode).
__global__ __launch_bounds__(256)
void gemm_packed(const unsigned short* __restrict__ G,
                 const unsigned short* __restrict__ Xu,
                 const unsigned short* __restrict__ Wraw,
                 const unsigned short* __restrict__ Wb,
                 const float* __restrict__ Bf,
                 float* __restrict__ Out,
                 const int* __restrict__ flag,
                 int b0)
{
    __shared__ __align__(16) unsigned short As[2][128 * 64];   // 64 KB total
    __shared__ __align__(16) unsigned short Bs[2][128 * 64];

    const int tid  = threadIdx.x;
    const int wave = tid >> 6;
    const int lane = tid & 63;
    const bool useX = (*flag == 0);          // bf16 inputs

    // bijective XCD swizzle (m204); N fast within M-panel.
    const int bid = blockIdx.x;
    const int nwg = gridDim.x;
    const int q = nwg >> 3, r = nwg & 7;
    const int xcd = bid & 7, s = bid >> 3;
    const int lid = (xcd < r ? xcd * (q + 1) : r * (q + 1) + (xcd - r) * q) + s;
    const int mT = lid / 6;                  // EMB/128 = 6 N-tiles
    const int nT = lid - mT * 6;
    const int mBase = mT * 128;              // chunk-local row base
    const int nBase = nT * 128;

    const int wm   = wave >> 1, wn = wave & 1;   // 2x2 waves of 64x64
    const int lrow = lane & 15;
    const int kq   = (lane >> 4) << 3;           // 0,8,16,24
    const int swz  = (lrow & 7) << 3;            // element XOR for ds_read

    const unsigned short* Wsrc = useX ? Wraw : Wb;

    floatx4 acc[4][4];
    #pragma unroll
    for (int i = 0; i < 4; i++)
        #pragma unroll
        for (int j = 0; j < 4; j++)
            acc[i][j] = (floatx4){0.f, 0.f, 0.f, 0.f};

    // staging map: idx=(i*4+wave)*64+lane; row=idx>>3, k8=idx&7.
    // linear LDS dest; inverse-swizzled global source chunk jc = k8 ^ (row&7).
    // odd level & bf16: base into X (odd rows are contiguous runs of X:
    // addr = (b0+b)*150528 + (111+l)*224 + k; channel step += 49728, c=kt/448
    // is exact because 448 = 7*64 so a 64-wide K-tile never straddles).
    const unsigned short* aP[4];
    int aExtra[4];
    unsigned aOff[4];
    #pragma unroll
    for (int i = 0; i < 4; i++) {
        const int idx = (i * 4 + wave) * 64 + lane;
        const int row = idx >> 3, k8 = idx & 7;
        const int jc  = k8 ^ (row & 7);
        const int m   = mBase + row;
        const int b   = m / NLEV;
        const int l   = m - b * NLEV;
        if ((l & 1) && useX) {
            aP[i] = Xu + (size_t)(b0 + b) * (CIN * IMG * IMG)
                       + (size_t)(111 + l) * IMG + jc * 8;
            aExtra[i] = 49728;               // plane step minus the 448 k-run
        } else {
            aP[i] = G + (size_t)m * DIN + jc * 8;
            aExtra[i] = 0;
        }
        aOff[i] = (unsigned)((i * 4 + wave) * 512);   // elements
    }
    const unsigned short* bP[4];
    unsigned bOff[4];
    #pragma unroll
    for (int i = 0; i < 4; i++) {
        const int idx = (i * 4 + wave) * 64 + lane;
        const int row = idx >> 3, k8 = idx & 7;
        const int jc  = k8 ^ (row & 7);
        bP[i] = Wsrc + (size_t)(nBase + row) * DIN + jc * 8;
        bOff[i] = (unsigned)((i * 4 + wave) * 512);
    }

    // prologue: stage tile 0 into buffer 0 (8 loads in flight)
    #pragma unroll
    for (int i = 0; i < 4; i++) {
        __builtin_amdgcn_global_load_lds((const AS1 void*)(aP[i]),
                                         (AS3 void*)(&As[0][0] + aOff[i]), 16, 0, 0);
        __builtin_amdgcn_global_load_lds((const AS1 void*)(bP[i]),
                                         (AS3 void*)(&Bs[0][0] + bOff[i]), 16, 0, 0);
    }

    int cur = 0;
    for (int t = 0; t < NT; ++t) {
        if (t < NT - 1) {
            const int kt = (t + 1) * 64;
            const int c  = kt / 448;                  // 0,1,2 (scalar)
            #pragma unroll
            for (int i = 0; i < 4; i++) {
                __builtin_amdgcn_global_load_lds(
                    (const AS1 void*)(aP[i] + kt + c * aExtra[i]),
                    (AS3 void*)(&As[cur ^ 1][0] + aOff[i]), 16, 0, 0);
                __builtin_amdgcn_global_load_lds(
                    (const AS1 void*)(bP[i] + kt),
                    (AS3 void*)(&Bs[cur ^ 1][0] + bOff[i]), 16, 0, 0);
            }
            // wait only for tile t's 8 loads; t+1's 8 stay in flight
            asm volatile("s_waitcnt vmcnt(8)" ::: "memory");
        } else {
            asm volatile("s_waitcnt vmcnt(0)" ::: "memory");
        }
        __builtin_amdgcn_s_barrier();        // all waves' tile-t data landed
        __builtin_amdgcn_sched_barrier(0);   // no ds_read hoisting above this

        const unsigned short* Ab = &As[cur][0];
        const unsigned short* Bb = &Bs[cur][0];
        #pragma unroll
        for (int k0 = 0; k0 < 64; k0 += 32) {
            short8 af[4], bfv[4];
            #pragma unroll
            for (int mi = 0; mi < 4; mi++)
                af[mi] = *(const short8*)&Ab[(wm * 64 + mi * 16 + lrow) * 64
                                             + ((k0 + kq) ^ swz)];
            #pragma unroll
            for (int ni = 0; ni < 4; ni++)
                bfv[ni] = *(const short8*)&Bb[(wn * 64 + ni * 16 + lrow) * 64
                                              + ((k0 + kq) ^ swz)];
            __builtin_amdgcn_s_setprio(1);
            #pragma unroll
            for (int mi = 0; mi < 4; mi++)
                #pragma unroll
                for (int ni = 0; ni < 4; ni++)
                    acc[mi][ni] = __builtin_amdgcn_mfma_f32_16x16x32_bf16(
                        af[mi], bfv[ni], acc[mi][ni], 0, 0, 0);
            __builtin_amdgcn_s_setprio(0);
        }
        __builtin_amdgcn_s_barrier();        // all waves done reading buf[cur]
        __builtin_amdgcn_sched_barrier(0);
        cur ^= 1;
    }

    // epilogue: C/D layout col=lane&15, row=(lane>>4)*4+reg (verified r5)
    const int quad = lane >> 4;
    #pragma unroll
    for (int ni = 0; ni < 4; ni++) {
        const int col = nBase + wn * 64 + ni * 16 + lrow;
        const float bv = Bf[col];
        #pragma unroll
        for (int mi = 0; mi < 4; mi++) {
            const int rbase = mBase + wm * 64 + mi * 16 + quad * 4;
            floatx4 a = acc[mi][ni];
            Out[(size_t)(rbase + 0) * EMB + col] = a[0] + bv;
            Out[(size_t)(rbase + 1) * EMB + col] = a[1] + bv;
            Out[(size_t)(rbase + 2) * EMB + col] = a[2] + bv;
            Out[(size_t)(rbase + 3) * EMB + col] = a[3] + bv;
        }
    }
}

// ---------------- Fallback: round-5 fused gather-GEMM (ws too small) ---------
template<bool F32>
__global__ __launch_bounds__(256, 2)
void lfreq_fused_gemm(const void* __restrict__ Xv,
                      const void* __restrict__ Wv,
                      const void* __restrict__ Bv,
                      const int* __restrict__ Aidx,
                      const int* __restrict__ Bidx,
                      float* __restrict__ Out,
                      const int* __restrict__ flag)
{
    if (*flag != (F32 ? 1 : 0)) return;

    __shared__ __align__(16) unsigned short As[BM][LDP];
    __shared__ __align__(16) unsigned short Bs[BN][LDP];

    const int tid   = threadIdx.x;
    const int wave  = tid >> 6;
    const int lane  = tid & 63;
    const int mBase = blockIdx.x * BM;
    const int nBase = blockIdx.y * BN;

    const int srow  = tid >> 1;
    const int shalf = tid & 1;
    const int am = mBase + srow;
    const int bb = am / NLEV;
    const int ll = am - bb * NLEV;

    floatx4 acc[4][4];
    #pragma unroll
    for (int i = 0; i < 4; i++)
        #pragma unroll
        for (int jj = 0; jj < 4; jj++)
            acc[i][jj] = (floatx4){0.f, 0.f, 0.f, 0.f};

    const int wm   = wave >> 1;
    const int wn   = wave & 1;
    const int lrow = lane & 15;
    const int kq   = (lane >> 4) << 3;

    for (int kt = 0; kt < DIN; kt += BK) {
        {
            const int koff = kt + shalf * 32;
            uint4* dst = (uint4*)&Bs[srow][shalf * 32];
            if (F32) {
                const float4* g = (const float4*)((const float*)Wv
                                + (size_t)(nBase + srow) * DIN + koff);
                #pragma unroll
                for (int q = 0; q < 4; q++) {
                    float4 v0 = g[2*q], v1 = g[2*q+1];
                    uint4 o;
                    o.x = pack2(v0.x, v0.y); o.y = pack2(v0.z, v0.w);
                    o.z = pack2(v1.x, v1.y); o.w = pack2(v1.z, v1.w);
                    dst[q] = o;
                }
            } else {
                const uint4* g = (const uint4*)((const unsigned short*)Wv
                               + (size_t)(nBase + srow) * DIN + koff);
                #pragma unroll
                for (int q = 0; q < 4; q++) dst[q] = g[q];
            }
        }
        {
            const int d0  = kt + shalf * 32;
            const int c   = (d0 >= 896) ? 2 : (d0 >= 448 ? 1 : 0);
            const int kk0 = d0 - c * 448;
            const int4* ap = (const int4*)(Aidx + ll * 448 + kk0);
            const int4* bp = (const int4*)(Bidx + ll * 448 + kk0);
            unsigned* du = (unsigned*)&As[srow][shalf * 32];
            if (F32) {
                const float* plane = (const float*)Xv
                    + (size_t)bb * (CIN * IMG * IMG) + (size_t)c * (IMG * IMG);
                #pragma unroll
                for (int q = 0; q < 8; q++) {
                    int4 av = ap[q], bv = bp[q];
                    du[2*q+0] = pack2(plane[av.x * IMG + bv.x], plane[av.y * IMG + bv.y]);
                    du[2*q+1] = pack2(plane[av.z * IMG + bv.z], plane[av.w * IMG + bv.w]);
                }
            } else {
                const unsigned short* plane = (const unsigned short*)Xv
                    + (size_t)bb * (CIN * IMG * IMG) + (size_t)c * (IMG * IMG);
                #pragma unroll
                for (int q = 0; q < 8; q++) {
                    int4 av = ap[q], bv = bp[q];
                    unsigned e0 = plane[av.x * IMG + bv.x];
                    unsigned e1 = plane[av.y * IMG + bv.y];
                    unsigned e2 = plane[av.z * IMG + bv.z];
                    unsigned e3 = plane[av.w * IMG + bv.w];
                    du[2*q+0] = e0 | (e1 << 16);
                    du[2*q+1] = e2 | (e3 << 16);
                }
            }
        }
        __syncthreads();

        #pragma unroll
        for (int k0 = 0; k0 < BK; k0 += 32) {
            short8 af[4], bfv[4];
            #pragma unroll
            for (int mi = 0; mi < 4; mi++)
                af[mi] = *(const short8*)&As[wm*64 + mi*16 + lrow][k0 + kq];
            #pragma unroll
            for (int ni = 0; ni < 4; ni++)
                bfv[ni] = *(const short8*)&Bs[wn*64 + ni*16 + lrow][k0 + kq];
            #pragma unroll
            for (int mi = 0; mi < 4; mi++)
                #pragma unroll
                for (int ni = 0; ni < 4; ni++)
                    acc[mi][ni] = __builtin_amdgcn_mfma_f32_16x16x32_bf16(
                        af[mi], bfv[ni], acc[mi][ni], 0, 0, 0);
        }
        __syncthreads();
    }

    const int quad = lane >> 4;
    #pragma unroll
    for (int ni = 0; ni < 4; ni++) {
        const int col = nBase + wn*64 + ni*16 + lrow;
        const float bv = F32 ? ((const float*)Bv)[col]
                             : bf2f(((const unsigned short*)Bv)[col]);
        #pragma unroll
        for (int mi = 0; mi < 4; mi++) {
            const int rbase = mBase + wm*64 + mi*16 + quad*4;
            floatx4 a = acc[mi][ni];
            Out[(size_t)(rbase+0)*EMB + col] = a[0] + bv;
            Out[(size_t)(rbase+1)*EMB + col] = a[1] + bv;
            Out[(size_t)(rbase+2)*EMB + col] = a[2] + bv;
            Out[(size_t)(rbase+3)*EMB + col] = a[3] + bv;
        }
    }
}

extern "C" void kernel_launch(void* const* d_in, const int* in_sizes, int n_in,
                              void* d_out, int out_size, void* d_ws, size_t ws_size,
                              hipStream_t stream) {
    const void* X    = d_in[0];              // x: [256,3,224,224]
    const void* Wt   = d_in[1];              // W: [768,1344]
    const void* Bias = d_in[2];              // b: [768]
    const int*  Ai   = (const int*)d_in[3];  // a_idx (unused in packed path)
    const int*  Bi   = (const int*)d_in[4];  // b_idx
    float* Out = (float*)d_out;              // f32 [256,112,768]

    char* ws  = (char*)d_ws;
    int* flag = (int*)ws;

    // workspace layout: [0] flag | [256] Bf f32[768] | [4096] Wb bf16[768*1344]
    //                   | [gOff] G chunk bf16[CHB*112*1344]
    float* Bf          = (float*)(ws + 256);
    unsigned short* Wb = (unsigned short*)(ws + 4096);
    const size_t gOff  = 4096 + (size_t)EMB * DIN * 2;        // 2,068,480
    unsigned short* Gc = (unsigned short*)(ws + gOff);

    int CHB = 0;
    const int cand[6] = {256, 128, 64, 32, 16, 8};   // *112 divisible by 128
    for (int t = 0; t < 6; t++) {
        if (gOff + (size_t)cand[t] * NLEV * DIN * 2 <= ws_size) { CHB = cand[t]; break; }
    }

    if (CHB == 0) {
        detect_dtype<<<dim3(1), dim3(256), 0, stream>>>((const unsigned short*)Wt, flag);
        dim3 grid(MTOT / BM, EMB / BN);
        lfreq_fused_gemm<false><<<grid, dim3(256), 0, stream>>>(X, Wt, Bias, Ai, Bi, Out, flag);
        lfreq_fused_gemm<true ><<<grid, dim3(256), 0, stream>>>(X, Wt, Bias, Ai, Bi, Out, flag);
        return;
    }

    for (int b0 = 0; b0 < BATCH; b0 += CHB) {
        dim3 pgrid(CHB, 4);
        pack_all<<<pgrid, dim3(256), 0, stream>>>(X, Wt, Bias, Gc, Wb, Bf, flag,
                                                  b0, CHB, b0 == 0 ? 1 : 0);
        dim3 ggrid(CHB * NLEV / 128 * 6);   // 1-D swizzled grid
        gemm_packed<<<ggrid, dim3(256), 0, stream>>>(
            Gc, (const unsigned short*)X, (const unsigned short*)Wt, Wb, Bf,
            Out + (size_t)b0 * NLEV * EMB, flag, b0);
    }
}